// Round 1
// baseline (174.500 us; speedup 1.0000x reference)
//
#include <hip/hip_runtime.h>
#include <hip/hip_bf16.h>

// Problem constants
#define BB 4
#define TT 1024
#define FF 512
#define HH 8
#define DKK 64
// SPAN=100, PAD_L=50, PAD_R=49; Vt padded rows of length 1152 (64 pad each side)
#define VROW 1152

typedef unsigned short u16;
typedef u16 u16x8 __attribute__((ext_vector_type(8)));
typedef __bf16 bf16x8 __attribute__((ext_vector_type(8)));
typedef float f32x4 __attribute__((ext_vector_type(4)));

__device__ __forceinline__ u16 f2bf(float f) {
  unsigned u = __builtin_bit_cast(unsigned, f);
  u += 0x7FFFu + ((u >> 16) & 1u);   // round-to-nearest-even
  return (u16)(u >> 16);
}

__device__ __forceinline__ f32x4 mfma16(u16x8 a, u16x8 b, f32x4 c) {
  return __builtin_amdgcn_mfma_f32_16x16x32_bf16(
      __builtin_bit_cast(bf16x8, a), __builtin_bit_cast(bf16x8, b), c, 0, 0, 0);
}

__device__ __forceinline__ u16x8 ld8(const u16* p) {
  return *reinterpret_cast<const u16x8*>(p);
}

// ---------------- 1) convert query/key/value fp32 -> bf16 ----------------
__global__ __launch_bounds__(256) void cvt_x(const float* __restrict__ q,
                                             const float* __restrict__ k,
                                             const float* __restrict__ v,
                                             u16* __restrict__ o) {
  long idx = ((long)blockIdx.x * 256 + threadIdx.x) * 8;  // 3*2097152 elems total
  const long NPER = (long)BB * TT * FF;                   // 2097152
  int w = (int)(idx / NPER);
  long lo = idx - (long)w * NPER;
  const float* s = (w == 0) ? q : ((w == 1) ? k : v);
  const float4* sp = reinterpret_cast<const float4*>(s + lo);
  float4 f0 = sp[0], f1 = sp[1];
  u16x8 r;
  r[0] = f2bf(f0.x); r[1] = f2bf(f0.y); r[2] = f2bf(f0.z); r[3] = f2bf(f0.w);
  r[4] = f2bf(f1.x); r[5] = f2bf(f1.y); r[6] = f2bf(f1.z); r[7] = f2bf(f1.w);
  *reinterpret_cast<u16x8*>(o + idx) = r;
}

// ---------------- 2) convert+transpose weights: Wt[w][n][k] = bf16(W[k][n]) ----------------
__global__ void cvt_w(const float* __restrict__ Wq, const float* __restrict__ Wk,
                      const float* __restrict__ Wv, const float* __restrict__ Wo,
                      u16* __restrict__ Wt) {
  __shared__ u16 tile[32][33];
  int w = blockIdx.z;
  const float* W = (w == 0) ? Wq : (w == 1) ? Wk : (w == 2) ? Wv : Wo;
  int n0 = blockIdx.x * 32, k0 = blockIdx.y * 32;
  int tx = threadIdx.x, ty = threadIdx.y;
#pragma unroll
  for (int i = 0; i < 4; i++) {
    int kk = ty + i * 8;
    tile[kk][tx] = f2bf(W[(size_t)(k0 + kk) * FF + n0 + tx]);
  }
  __syncthreads();
#pragma unroll
  for (int i = 0; i < 4; i++) {
    int nn = ty + i * 8;
    Wt[(size_t)w * FF * FF + (size_t)(n0 + nn) * FF + k0 + tx] = tile[tx][nn];
  }
}

// ---------------- 3) QKV projection GEMM (bf16 MFMA) ----------------
// grid (M/64, N/64, 3); block 256 (4 waves, 2x2 of 32x32 wave tiles)
__global__ __launch_bounds__(256) void gemm_qkv(
    const u16* __restrict__ Xc, const u16* __restrict__ Wt,
    const float* __restrict__ bq, const float* __restrict__ bk,
    const float* __restrict__ bv,
    u16* __restrict__ Qb, u16* __restrict__ Kb, u16* __restrict__ Vt) {
  int z = blockIdx.z;
  const u16* A = Xc + (size_t)z * BB * TT * FF;
  const u16* Bt = Wt + (size_t)z * FF * FF;
  const float* bias = (z == 0) ? bq : ((z == 1) ? bk : bv);
  int tid = threadIdx.x, wid = tid >> 6, lane = tid & 63;
  int cl = lane & 15, g = lane >> 4;
  int m0 = blockIdx.x * 64 + (wid >> 1) * 32;
  int n0 = blockIdx.y * 64 + (wid & 1) * 32;
  f32x4 acc[2][2] = {};
  const u16* a0p = A + (size_t)(m0 + cl) * FF + g * 8;
  const u16* a1p = a0p + (size_t)16 * FF;
  const u16* b0p = Bt + (size_t)(n0 + cl) * FF + g * 8;
  const u16* b1p = b0p + (size_t)16 * FF;
#pragma unroll 4
  for (int k0 = 0; k0 < FF; k0 += 32) {
    u16x8 a0 = ld8(a0p + k0), a1 = ld8(a1p + k0);
    u16x8 w0 = ld8(b0p + k0), w1 = ld8(b1p + k0);
    acc[0][0] = mfma16(a0, w0, acc[0][0]);
    acc[0][1] = mfma16(a0, w1, acc[0][1]);
    acc[1][0] = mfma16(a1, w0, acc[1][0]);
    acc[1][1] = mfma16(a1, w1, acc[1][1]);
  }
#pragma unroll
  for (int rt = 0; rt < 2; rt++)
#pragma unroll
    for (int ct = 0; ct < 2; ct++)
#pragma unroll
      for (int r = 0; r < 4; r++) {
        int m = m0 + rt * 16 + g * 4 + r;
        int n = n0 + ct * 16 + cl;
        float v = acc[rt][ct][r] + bias[n];
        int b = m >> 10, t = m & 1023, h = n >> 6, d = n & 63;
        size_t bh = (size_t)b * HH + h;
        if (z == 0)
          Qb[(bh * TT + t) * DKK + d] = f2bf(v * 0.125f);  // 1/sqrt(64)
        else if (z == 1)
          Kb[(bh * TT + t) * DKK + d] = f2bf(v);
        else
          Vt[(bh * DKK + d) * VROW + 64 + t] = f2bf(v);    // transposed, padded
      }
}

// ---------------- 4) banded attention ----------------
// grid 512, block 256; wave w of block bid handles q-tile (bid&15)*4+w of bh=bid>>4
__global__ __launch_bounds__(256) void attn(const u16* __restrict__ Qb,
                                            const u16* __restrict__ Kb,
                                            const u16* __restrict__ Vt,
                                            const int* __restrict__ mask,
                                            u16* __restrict__ X2) {
  __shared__ u16 plds[4][16][128];
  int tid = threadIdx.x, wid = tid >> 6, lane = tid & 63;
  int cl = lane & 15, g = lane >> 4;
  int bh = blockIdx.x >> 4;
  int qt = ((blockIdx.x & 15) << 2) + wid;
  int t0 = qt << 4;
  int b = bh >> 3, h = bh & 7;

  const u16* qrow = Qb + ((size_t)bh * TT + t0 + cl) * DKK + g * 8;
  u16x8 qa0 = ld8(qrow);
  u16x8 qa1 = ld8(qrow + 32);

  f32x4 s[8];
#pragma unroll
  for (int c = 0; c < 8; c++) {
    int kt = t0 - 50 + c * 16 + cl;                 // key position
    bool inr = (kt >= 0) && (kt < TT);
    bool valid = inr && (mask[b * TT + (inr ? kt : 0)] != 0);
    u16x8 kb0 = {0, 0, 0, 0, 0, 0, 0, 0}, kb1 = {0, 0, 0, 0, 0, 0, 0, 0};
    if (inr) {
      const u16* kp = Kb + ((size_t)bh * TT + kt) * DKK + g * 8;
      kb0 = ld8(kp);
      kb1 = ld8(kp + 32);
    }
    f32x4 acc = {0.f, 0.f, 0.f, 0.f};
    acc = mfma16(qa0, kb0, acc);
    acc = mfma16(qa1, kb1, acc);
#pragma unroll
    for (int r = 0; r < 4; r++) {
      int row = g * 4 + r;          // q row within tile
      int j = c * 16 + cl;          // key index within 128 window
      int sp = j - row;             // span offset: valid iff 0<=sp<100
      bool ok = valid && (sp >= 0) && (sp < 100);
      acc[r] = ok ? acc[r] : -1e30f;
    }
    s[c] = acc;
  }

  // exact softmax per q row (row lives in one 16-lane group, reg r)
#pragma unroll
  for (int r = 0; r < 4; r++) {
    float m = s[0][r];
#pragma unroll
    for (int c = 1; c < 8; c++) m = fmaxf(m, s[c][r]);
    m = fmaxf(m, __shfl_xor(m, 1, 64));
    m = fmaxf(m, __shfl_xor(m, 2, 64));
    m = fmaxf(m, __shfl_xor(m, 4, 64));
    m = fmaxf(m, __shfl_xor(m, 8, 64));
    float sum = 0.f;
#pragma unroll
    for (int c = 0; c < 8; c++) {
      float p = __expf(s[c][r] - m);
      s[c][r] = p;
      sum += p;
    }
    sum += __shfl_xor(sum, 1, 64);
    sum += __shfl_xor(sum, 2, 64);
    sum += __shfl_xor(sum, 4, 64);
    sum += __shfl_xor(sum, 8, 64);
    float inv = 1.0f / sum;
#pragma unroll
    for (int c = 0; c < 8; c++) s[c][r] *= inv;
  }

  // P (C-layout) -> LDS (swizzled) -> A-layout fragments
#pragma unroll
  for (int c = 0; c < 8; c++)
#pragma unroll
    for (int r = 0; r < 4; r++) {
      int row = g * 4 + r;
      int col = (c * 16 + cl) ^ ((row & 7) << 3);
      plds[wid][row][col] = f2bf(s[c][r]);
    }
  __syncthreads();

  u16x8 pa[4];
#pragma unroll
  for (int ks = 0; ks < 4; ks++) {
    int jb = (ks * 32 + g * 8) ^ ((cl & 7) << 3);
    pa[ks] = ld8(&plds[wid][cl][jb]);
  }

  f32x4 o[4] = {};
  const u16* vbase = Vt + (size_t)bh * DKK * VROW;
#pragma unroll
  for (int nt = 0; nt < 4; nt++) {
    int d = nt * 16 + cl;
    const u16* vp = vbase + (size_t)d * VROW + (t0 + 14 + g * 8);  // 64-50=14
#pragma unroll
    for (int ks = 0; ks < 4; ks++) o[nt] = mfma16(pa[ks], ld8(vp + ks * 32), o[nt]);
  }

#pragma unroll
  for (int nt = 0; nt < 4; nt++)
#pragma unroll
    for (int r = 0; r < 4; r++) {
      int t = t0 + g * 4 + r;
      int f = h * 64 + nt * 16 + cl;
      X2[((size_t)b * TT + t) * FF + f] = f2bf(o[nt][r]);
    }
}

// ---------------- 5) output projection GEMM (fp32 out + bias) ----------------
__global__ __launch_bounds__(256) void gemm_out(const u16* __restrict__ X2,
                                                const u16* __restrict__ Wto,
                                                const float* __restrict__ bo,
                                                float* __restrict__ out) {
  int tid = threadIdx.x, wid = tid >> 6, lane = tid & 63;
  int cl = lane & 15, g = lane >> 4;
  int m0 = blockIdx.x * 64 + (wid >> 1) * 32;
  int n0 = blockIdx.y * 64 + (wid & 1) * 32;
  f32x4 acc[2][2] = {};
  const u16* a0p = X2 + (size_t)(m0 + cl) * FF + g * 8;
  const u16* a1p = a0p + (size_t)16 * FF;
  const u16* b0p = Wto + (size_t)(n0 + cl) * FF + g * 8;
  const u16* b1p = b0p + (size_t)16 * FF;
#pragma unroll 4
  for (int k0 = 0; k0 < FF; k0 += 32) {
    u16x8 a0 = ld8(a0p + k0), a1 = ld8(a1p + k0);
    u16x8 w0 = ld8(b0p + k0), w1 = ld8(b1p + k0);
    acc[0][0] = mfma16(a0, w0, acc[0][0]);
    acc[0][1] = mfma16(a0, w1, acc[0][1]);
    acc[1][0] = mfma16(a1, w0, acc[1][0]);
    acc[1][1] = mfma16(a1, w1, acc[1][1]);
  }
#pragma unroll
  for (int rt = 0; rt < 2; rt++)
#pragma unroll
    for (int ct = 0; ct < 2; ct++)
#pragma unroll
      for (int r = 0; r < 4; r++) {
        int m = m0 + rt * 16 + g * 4 + r;
        int n = n0 + ct * 16 + cl;
        out[(size_t)m * FF + n] = acc[rt][ct][r] + bo[n];
      }
}

extern "C" void kernel_launch(void* const* d_in, const int* in_sizes, int n_in,
                              void* d_out, int out_size, void* d_ws, size_t ws_size,
                              hipStream_t stream) {
  const float* query = (const float*)d_in[0];
  const float* key_i = (const float*)d_in[1];
  const float* value = (const float*)d_in[2];
  const int* mask = (const int*)d_in[3];
  const float* Wq = (const float*)d_in[4];
  const float* bq = (const float*)d_in[5];
  const float* Wk = (const float*)d_in[6];
  const float* bk = (const float*)d_in[7];
  const float* Wv = (const float*)d_in[8];
  const float* bv = (const float*)d_in[9];
  const float* Wo = (const float*)d_in[10];
  const float* bo = (const float*)d_in[11];
  float* out = (float*)d_out;

  char* ws = (char*)d_ws;
  u16* Xc = (u16*)(ws + 0);            // 3 * 2M elems bf16  = 12,582,912 B
  u16* Wt = (u16*)(ws + 12582912);     // 4 * 256K elems     =  2,097,152 B
  u16* Qb = (u16*)(ws + 14680064);     // [32][1024][64]     =  4,194,304 B
  u16* Kb = (u16*)(ws + 18874368);     // [32][1024][64]     =  4,194,304 B
  u16* Vt = (u16*)(ws + 23068672);     // [32][64][1152]     =  4,718,592 B
  u16* X2 = (u16*)(ws + 27787264);     // [4096][512]        =  4,194,304 B

  hipLaunchKernelGGL(cvt_x, dim3(3072), dim3(256), 0, stream, query, key_i, value, Xc);
  hipLaunchKernelGGL(cvt_w, dim3(16, 16, 4), dim3(32, 8), 0, stream, Wq, Wk, Wv, Wo, Wt);
  hipLaunchKernelGGL(gemm_qkv, dim3(64, 8, 3), dim3(256), 0, stream,
                     Xc, Wt, bq, bk, bv, Qb, Kb, Vt);
  hipLaunchKernelGGL(attn, dim3(512), dim3(256), 0, stream, Qb, Kb, Vt, mask, X2);
  hipLaunchKernelGGL(gemm_out, dim3(64, 8), dim3(256), 0, stream,
                     X2, Wt + (size_t)3 * FF * FF, bo, out);
}

// Round 15
// 144.049 us; speedup vs baseline: 1.2114x; 1.2114x over previous
//
#include <hip/hip_runtime.h>
#include <hip/hip_bf16.h>

// Problem constants
#define BB 4
#define TT 1024
#define FF 512
#define HH 8
#define DKK 64
// SPAN=100, PAD_L=50, PAD_R=49; Vt padded rows of length 1152 (64 pad each side)
#define VROW 1152
#define BKK 32

typedef unsigned short u16;
typedef u16 u16x8 __attribute__((ext_vector_type(8)));
typedef __bf16 bf16x8 __attribute__((ext_vector_type(8)));
typedef float f32x4 __attribute__((ext_vector_type(4)));

__device__ __forceinline__ u16 f2bf(float f) {
  unsigned u = __builtin_bit_cast(unsigned, f);
  u += 0x7FFFu + ((u >> 16) & 1u);   // round-to-nearest-even
  return (u16)(u >> 16);
}

__device__ __forceinline__ f32x4 mfma16(u16x8 a, u16x8 b, f32x4 c) {
  return __builtin_amdgcn_mfma_f32_16x16x32_bf16(
      __builtin_bit_cast(bf16x8, a), __builtin_bit_cast(bf16x8, b), c, 0, 0, 0);
}

__device__ __forceinline__ u16x8 ld8(const u16* p) {
  return *reinterpret_cast<const u16x8*>(p);
}

#define GLDS16(gp, lp)                                              \
  __builtin_amdgcn_global_load_lds(                                 \
      (const __attribute__((address_space(1))) void*)(gp),          \
      (__attribute__((address_space(3))) void*)(lp), 16, 0, 0)

// ---------------- 1) convert query/key/value fp32 -> bf16 ----------------
__global__ __launch_bounds__(256) void cvt_x(const float* __restrict__ q,
                                             const float* __restrict__ k,
                                             const float* __restrict__ v,
                                             u16* __restrict__ o) {
  long idx = ((long)blockIdx.x * 256 + threadIdx.x) * 8;  // 3*2097152 elems total
  const long NPER = (long)BB * TT * FF;                   // 2097152
  int w = (int)(idx / NPER);
  long lo = idx - (long)w * NPER;
  const float* s = (w == 0) ? q : ((w == 1) ? k : v);
  const float4* sp = reinterpret_cast<const float4*>(s + lo);
  float4 f0 = sp[0], f1 = sp[1];
  u16x8 r;
  r[0] = f2bf(f0.x); r[1] = f2bf(f0.y); r[2] = f2bf(f0.z); r[3] = f2bf(f0.w);
  r[4] = f2bf(f1.x); r[5] = f2bf(f1.y); r[6] = f2bf(f1.z); r[7] = f2bf(f1.w);
  *reinterpret_cast<u16x8*>(o + idx) = r;
}

// ---------------- 2) convert+transpose weights: Wt[w][n][k] = bf16(W[k][n]) ----------------
__global__ void cvt_w(const float* __restrict__ Wq, const float* __restrict__ Wk,
                      const float* __restrict__ Wv, const float* __restrict__ Wo,
                      u16* __restrict__ Wt) {
  __shared__ u16 tile[32][33];
  int w = blockIdx.z;
  const float* W = (w == 0) ? Wq : (w == 1) ? Wk : (w == 2) ? Wv : Wo;
  int n0 = blockIdx.x * 32, k0 = blockIdx.y * 32;
  int tx = threadIdx.x, ty = threadIdx.y;
#pragma unroll
  for (int i = 0; i < 4; i++) {
    int kk = ty + i * 8;
    tile[kk][tx] = f2bf(W[(size_t)(k0 + kk) * FF + n0 + tx]);
  }
  __syncthreads();
#pragma unroll
  for (int i = 0; i < 4; i++) {
    int nn = ty + i * 8;
    Wt[(size_t)w * FF * FF + (size_t)(n0 + nn) * FF + k0 + tx] = tile[tx][nn];
  }
}

// ---------------- GEMM core: 128x128 tile, BK=32, LDS-staged (m97 structure) ----------------
// A is [M][512] row-major bf16, Bt is [N][512] row-major bf16 (i.e. B^T).
// 4 waves (2x2), each computes a 64x64 sub-tile as 4x4 MFMA fragments.
__device__ __forceinline__ void gemm_tile_core(const u16* __restrict__ A,
                                               const u16* __restrict__ Bt,
                                               u16* As, u16* Bs,
                                               int m_base, int n_base,
                                               f32x4 (&acc)[4][4]) {
  int tid = threadIdx.x, wid = tid >> 6, lane = tid & 63;
  int cl = lane & 15, g = lane >> 4;
  int wm = (wid >> 1) * 64, wn = (wid & 1) * 64;

  // staging: thread t covers row t/4 (within 64-row half), cols (t&3)*8 .. +8
  int srow = tid >> 2;
  int scol = (tid & 3) * 8;
  const u16* ga0 = A + (size_t)(m_base + srow) * FF + scol;
  const u16* ga1 = ga0 + (size_t)64 * FF;
  const u16* gb0 = Bt + (size_t)(n_base + srow) * FF + scol;
  const u16* gb1 = gb0 + (size_t)64 * FF;
  u16* la0 = As + wid * 512;          // wave-uniform LDS dest bases
  u16* la1 = As + 2048 + wid * 512;
  u16* lb0 = Bs + wid * 512;
  u16* lb1 = Bs + 2048 + wid * 512;

  const u16* ra = As + (wm + cl) * BKK + g * 8;
  const u16* rb = Bs + (wn + cl) * BKK + g * 8;

  for (int k0 = 0; k0 < FF; k0 += BKK) {
    if (k0) __syncthreads();          // previous tile's reads complete
    GLDS16(ga0 + k0, la0);
    GLDS16(ga1 + k0, la1);
    GLDS16(gb0 + k0, lb0);
    GLDS16(gb1 + k0, lb1);
    __syncthreads();                  // drains vmcnt -> LDS tile ready

    u16x8 af[4], bf[4];
#pragma unroll
    for (int i = 0; i < 4; i++) {
      af[i] = ld8(ra + i * 16 * BKK);
      bf[i] = ld8(rb + i * 16 * BKK);
    }
#pragma unroll
    for (int mf = 0; mf < 4; mf++)
#pragma unroll
      for (int nf = 0; nf < 4; nf++)
        acc[mf][nf] = mfma16(af[mf], bf[nf], acc[mf][nf]);
  }
}

// ---------------- 3) fused QKV projection GEMM: M=4096, N=1536 ----------------
__global__ __launch_bounds__(256, 3) void gemm_qkv(
    const u16* __restrict__ Xc, const u16* __restrict__ Wt,
    const float* __restrict__ bq, const float* __restrict__ bk,
    const float* __restrict__ bv,
    u16* __restrict__ Qb, u16* __restrict__ Kb, u16* __restrict__ Vt) {
  __shared__ u16 As[128 * BKK];
  __shared__ u16 Bs[128 * BKK];
  int m_base = blockIdx.x * 128;
  int n_base = blockIdx.y * 128;          // 0..1535, z = n_base>>9 uniform
  int z = n_base >> 9;
  // A-matrix differs per z: z=0 -> query, z=1 -> key, z=2 -> value  (BUGFIX)
  const u16* A = Xc + (size_t)z * (BB * TT * FF);
  f32x4 acc[4][4] = {};
  gemm_tile_core(A, Wt, As, Bs, m_base, n_base, acc);

  const float* bias = (z == 0) ? bq : ((z == 1) ? bk : bv);
  int tid = threadIdx.x, wid = tid >> 6, lane = tid & 63;
  int cl = lane & 15, g = lane >> 4;
  int wm = (wid >> 1) * 64, wn = (wid & 1) * 64;
  int nb = n_base & 511;
#pragma unroll
  for (int mf = 0; mf < 4; mf++)
#pragma unroll
    for (int nf = 0; nf < 4; nf++)
#pragma unroll
      for (int r = 0; r < 4; r++) {
        int m = m_base + wm + mf * 16 + g * 4 + r;
        int nl = nb + wn + nf * 16 + cl;      // 0..511 within this z
        float v = acc[mf][nf][r] + bias[nl];
        int b = m >> 10, t = m & 1023, h = nl >> 6, d = nl & 63;
        size_t bh = (size_t)b * HH + h;
        if (z == 0)
          Qb[(bh * TT + t) * DKK + d] = f2bf(v * 0.125f);   // 1/sqrt(64)
        else if (z == 1)
          Kb[(bh * TT + t) * DKK + d] = f2bf(v);
        else
          Vt[(bh * DKK + d) * VROW + 64 + t] = f2bf(v);     // transposed, padded
      }
}

// ---------------- 4) banded attention: 1 wave per 16-row q-tile ----------------
__global__ __launch_bounds__(64) void attn(const u16* __restrict__ Qb,
                                           const u16* __restrict__ Kb,
                                           const u16* __restrict__ Vt,
                                           const int* __restrict__ mask,
                                           u16* __restrict__ X2) {
  __shared__ u16 plds[16][128];
  int lane = threadIdx.x & 63;
  int cl = lane & 15, g = lane >> 4;
  int bh = blockIdx.x >> 6;
  int qt = blockIdx.x & 63;
  int t0 = qt << 4;
  int b = bh >> 3, h = bh & 7;

  const u16* qrow = Qb + ((size_t)bh * TT + t0 + cl) * DKK + g * 8;
  u16x8 qa0 = ld8(qrow);
  u16x8 qa1 = ld8(qrow + 32);

  f32x4 s[8];
#pragma unroll
  for (int c = 0; c < 8; c++) {
    int kt = t0 - 50 + c * 16 + cl;                 // key position
    bool inr = (kt >= 0) && (kt < TT);
    bool valid = inr && (mask[b * TT + (inr ? kt : 0)] != 0);
    u16x8 kb0 = {0, 0, 0, 0, 0, 0, 0, 0}, kb1 = {0, 0, 0, 0, 0, 0, 0, 0};
    if (inr) {
      const u16* kp = Kb + ((size_t)bh * TT + kt) * DKK + g * 8;
      kb0 = ld8(kp);
      kb1 = ld8(kp + 32);
    }
    f32x4 acc = {0.f, 0.f, 0.f, 0.f};
    acc = mfma16(qa0, kb0, acc);
    acc = mfma16(qa1, kb1, acc);
#pragma unroll
    for (int r = 0; r < 4; r++) {
      int row = g * 4 + r;          // q row within tile
      int j = c * 16 + cl;          // key index within 128 window
      int sp = j - row;             // span offset: valid iff 0<=sp<100
      bool ok = valid && (sp >= 0) && (sp < 100);
      acc[r] = ok ? acc[r] : -1e30f;
    }
    s[c] = acc;
  }

  // exact softmax per q row (row lives in one 16-lane group, reg r)
#pragma unroll
  for (int r = 0; r < 4; r++) {
    float m = s[0][r];
#pragma unroll
    for (int c = 1; c < 8; c++) m = fmaxf(m, s[c][r]);
    m = fmaxf(m, __shfl_xor(m, 1, 64));
    m = fmaxf(m, __shfl_xor(m, 2, 64));
    m = fmaxf(m, __shfl_xor(m, 4, 64));
    m = fmaxf(m, __shfl_xor(m, 8, 64));
    float sum = 0.f;
#pragma unroll
    for (int c = 0; c < 8; c++) {
      float p = __expf(s[c][r] - m);
      s[c][r] = p;
      sum += p;
    }
    sum += __shfl_xor(sum, 1, 64);
    sum += __shfl_xor(sum, 2, 64);
    sum += __shfl_xor(sum, 4, 64);
    sum += __shfl_xor(sum, 8, 64);
    float inv = 1.0f / sum;
#pragma unroll
    for (int c = 0; c < 8; c++) s[c][r] *= inv;
  }

  // P (C-layout) -> LDS (swizzled) -> A-layout fragments
#pragma unroll
  for (int c = 0; c < 8; c++)
#pragma unroll
    for (int r = 0; r < 4; r++) {
      int row = g * 4 + r;
      int col = (c * 16 + cl) ^ ((row & 7) << 3);
      plds[row][col] = f2bf(s[c][r]);
    }
  __syncthreads();

  u16x8 pa[4];
#pragma unroll
  for (int ks = 0; ks < 4; ks++) {
    int jb = (ks * 32 + g * 8) ^ ((cl & 7) << 3);
    pa[ks] = ld8(&plds[cl][jb]);
  }

  f32x4 o[4] = {};
  const u16* vbase = Vt + (size_t)bh * DKK * VROW;
#pragma unroll
  for (int nt = 0; nt < 4; nt++) {
    int d = nt * 16 + cl;
    const u16* vp = vbase + (size_t)d * VROW + (t0 + 14 + g * 8);  // 64-50=14
#pragma unroll
    for (int ks = 0; ks < 4; ks++) o[nt] = mfma16(pa[ks], ld8(vp + ks * 32), o[nt]);
  }

#pragma unroll
  for (int nt = 0; nt < 4; nt++)
#pragma unroll
    for (int r = 0; r < 4; r++) {
      int t = t0 + g * 4 + r;
      int f = h * 64 + nt * 16 + cl;
      X2[((size_t)b * TT + t) * FF + f] = f2bf(o[nt][r]);
    }
}

// ---------------- 5) output projection GEMM (fp32 out + bias) ----------------
__global__ __launch_bounds__(256, 3) void gemm_out(const u16* __restrict__ X2,
                                                   const u16* __restrict__ Wto,
                                                   const float* __restrict__ bo,
                                                   float* __restrict__ out) {
  __shared__ u16 As[128 * BKK];
  __shared__ u16 Bs[128 * BKK];
  int m_base = blockIdx.x * 128;
  int n_base = blockIdx.y * 128;
  f32x4 acc[4][4] = {};
  gemm_tile_core(X2, Wto, As, Bs, m_base, n_base, acc);

  int tid = threadIdx.x, wid = tid >> 6, lane = tid & 63;
  int cl = lane & 15, g = lane >> 4;
  int wm = (wid >> 1) * 64, wn = (wid & 1) * 64;
#pragma unroll
  for (int mf = 0; mf < 4; mf++)
#pragma unroll
    for (int nf = 0; nf < 4; nf++)
#pragma unroll
      for (int r = 0; r < 4; r++) {
        int m = m_base + wm + mf * 16 + g * 4 + r;
        int n = n_base + wn + nf * 16 + cl;
        out[(size_t)m * FF + n] = acc[mf][nf][r] + bo[n];
      }
}

extern "C" void kernel_launch(void* const* d_in, const int* in_sizes, int n_in,
                              void* d_out, int out_size, void* d_ws, size_t ws_size,
                              hipStream_t stream) {
  const float* query = (const float*)d_in[0];
  const float* key_i = (const float*)d_in[1];
  const float* value = (const float*)d_in[2];
  const int* mask = (const int*)d_in[3];
  const float* Wq = (const float*)d_in[4];
  const float* bq = (const float*)d_in[5];
  const float* Wk = (const float*)d_in[6];
  const float* bk = (const float*)d_in[7];
  const float* Wv = (const float*)d_in[8];
  const float* bv = (const float*)d_in[9];
  const float* Wo = (const float*)d_in[10];
  const float* bo = (const float*)d_in[11];
  float* out = (float*)d_out;

  char* ws = (char*)d_ws;
  u16* Xc = (u16*)(ws + 0);            // 3 * 2M elems bf16  = 12,582,912 B
  u16* Wt = (u16*)(ws + 12582912);     // 4 * 256K elems     =  2,097,152 B
  u16* Qb = (u16*)(ws + 14680064);     // [32][1024][64]     =  4,194,304 B
  u16* Kb = (u16*)(ws + 18874368);     // [32][1024][64]     =  4,194,304 B
  u16* Vt = (u16*)(ws + 23068672);     // [32][64][1152]     =  4,718,592 B
  u16* X2 = (u16*)(ws + 27787264);     // [4096][512]        =  4,194,304 B

  hipLaunchKernelGGL(cvt_x, dim3(3072), dim3(256), 0, stream, query, key_i, value, Xc);
  hipLaunchKernelGGL(cvt_w, dim3(16, 16, 4), dim3(32, 8), 0, stream, Wq, Wk, Wv, Wo, Wt);
  hipLaunchKernelGGL(gemm_qkv, dim3(32, 12), dim3(256), 0, stream,
                     Xc, Wt, bq, bk, bv, Qb, Kb, Vt);
  hipLaunchKernelGGL(attn, dim3(2048), dim3(64), 0, stream, Qb, Kb, Vt, mask, X2);
  hipLaunchKernelGGL(gemm_out, dim3(32, 4), dim3(256), 0, stream,
                     X2, Wt + (size_t)3 * FF * FF, bo, out);
}